// Round 4
// baseline (247.413 us; speedup 1.0000x reference)
//
#include <hip/hip_runtime.h>
#include <math.h>

// out[b] = log( sum_kk (w[kk>>8]*W0[kk,x0[b]]) * W1[kk,x1[b]] ),  kk in [0,65536)
//
// Fused single kernel: 256 blocks (1/CU), block = split of 256 kk (one latent
// k -> w_sum is a block-uniform scalar). Each block computes the full 256x256
// MFMA tile for its split (W read exactly once, 134 MB floor), then instead of
// storing the 256 KB tile, dumps it to LDS (2 waves/phase, 4 phases) and
// gathers ONLY the 1024 observed (x0,x1) pair values, atomically accumulated
// into S_b[1024] (4 KB). Last-block-done protocol computes log() in-kernel.

#define SPLITS  256
#define KCHUNK  256
#define BK      32
#define NITER   (KCHUNK / BK)   // 8
#define LDSS    40              // shorts per c-row in staging: 32 k + 8 pad

typedef float  f32x4  __attribute__((ext_vector_type(4)));
typedef short  bf16x8 __attribute__((ext_vector_type(8)));

static __device__ __forceinline__ short f2bf(float f) {
    // RNE fp32 -> bf16 (inputs are positive probabilities; no NaN/Inf)
    unsigned u = __builtin_bit_cast(unsigned, f);
    u += 0x7fffu + ((u >> 16) & 1u);
    return (short)(u >> 16);
}

__global__ __launch_bounds__(512, 2) void hclt_fused_kernel(
    const int* __restrict__ x, const float* __restrict__ W,
    const float* __restrict__ wsum, float* __restrict__ S_b,
    int* __restrict__ counter, float* __restrict__ out)
{
    // staging: As[2] 20 KB + Bs[2] 20 KB = 80 KB; epilogue reuses it as the
    // gather buffer (2 waves x 64 x 129 floats = 66 KB)
    __shared__ __align__(16) char smem[81920];
    __shared__ int pairs[1024];
    __shared__ int lastFlag;

    short* const AsB[2] = { (short*)smem,           (short*)(smem + 20480) };
    short* const BsB[2] = { (short*)(smem + 40960), (short*)(smem + 61440) };
    float* const gat    = (float*)smem;   // [buf][c0loc(64) x 129]

    const int  split = blockIdx.x;             // 0..255
    const long kbase = (long)split * KCHUNK;
    const float wk   = wsum[split];            // block-uniform

    const float* __restrict__ Ag = W + kbase * 256;              // W0 rows
    const float* __restrict__ Bg = W + 16777216 + kbase * 256;   // W1 rows

    const int t  = threadIdx.x;
    const int cq = (t & 63) * 4;    // c-quad this thread stages
    const int kq = (t >> 6) * 4;    // k-quad

    const int lane = t & 63;
    const int wv   = t >> 6;             // wave 0..7
    const int wc0  = (wv & 3) * 64;      // 4 wave-tiles along c0
    const int wc1  = (wv >> 2) * 128;    // 2 along c1
    const int ml   = lane & 15;
    const int qd   = lane >> 4;

    // load observed pairs into LDS (visible after the first __syncthreads)
    {
        const int2 x0 = ((const int2*)x)[t];
        const int2 x1 = ((const int2*)x)[t + 512];
        pairs[t]       = (x0.x << 8) | x0.y;
        pairs[t + 512] = (x1.x << 8) | x1.y;
    }

    f32x4 acc[4][8];
#pragma unroll
    for (int i = 0; i < 4; ++i)
#pragma unroll
        for (int j = 0; j < 8; ++j) acc[i][j] = (f32x4){0.f, 0.f, 0.f, 0.f};

    float4 a4[4], b4[4];

    // ---- prologue: load + stage iter 0 ----
#pragma unroll
    for (int r = 0; r < 4; ++r) {
        a4[r] = *(const float4*)(Ag + (long)(kq + r) * 256 + cq);
        b4[r] = *(const float4*)(Bg + (long)(kq + r) * 256 + cq);
    }
    {
        const float* af32 = reinterpret_cast<const float*>(a4);
        const float* bf32 = reinterpret_cast<const float*>(b4);
#pragma unroll
        for (int j = 0; j < 4; ++j) {
            short4 av, bv;
            av.x = f2bf(af32[0 * 4 + j] * wk);
            av.y = f2bf(af32[1 * 4 + j] * wk);
            av.z = f2bf(af32[2 * 4 + j] * wk);
            av.w = f2bf(af32[3 * 4 + j] * wk);
            bv.x = f2bf(bf32[0 * 4 + j]);
            bv.y = f2bf(bf32[1 * 4 + j]);
            bv.z = f2bf(bf32[2 * 4 + j]);
            bv.w = f2bf(bf32[3 * 4 + j]);
            *(short4*)&AsB[0][(cq + j) * LDSS + kq] = av;
            *(short4*)&BsB[0][(cq + j) * LDSS + kq] = bv;
        }
    }
    __syncthreads();

    // ---- pipelined main loop ----
#pragma unroll
    for (int it = 0; it < NITER; ++it) {
        const int cur = it & 1;
        if (it + 1 < NITER) {
#pragma unroll
            for (int r = 0; r < 4; ++r) {
                a4[r] = *(const float4*)(Ag + (long)((it + 1) * BK + kq + r) * 256 + cq);
                b4[r] = *(const float4*)(Bg + (long)((it + 1) * BK + kq + r) * 256 + cq);
            }
        }
        bf16x8 afr[4];
#pragma unroll
        for (int mi = 0; mi < 4; ++mi)
            afr[mi] = *(const bf16x8*)&AsB[cur][(wc0 + mi * 16 + ml) * LDSS + qd * 8];
#pragma unroll
        for (int ni = 0; ni < 8; ++ni) {
            const bf16x8 bfr = *(const bf16x8*)&BsB[cur][(wc1 + ni * 16 + ml) * LDSS + qd * 8];
#pragma unroll
            for (int mi = 0; mi < 4; ++mi)
                acc[mi][ni] = __builtin_amdgcn_mfma_f32_16x16x32_bf16(
                    afr[mi], bfr, acc[mi][ni], 0, 0, 0);
        }
        if (it + 1 < NITER) {
            const float* af32 = reinterpret_cast<const float*>(a4);
            const float* bf32 = reinterpret_cast<const float*>(b4);
#pragma unroll
            for (int j = 0; j < 4; ++j) {
                short4 av, bv;
                av.x = f2bf(af32[0 * 4 + j] * wk);
                av.y = f2bf(af32[1 * 4 + j] * wk);
                av.z = f2bf(af32[2 * 4 + j] * wk);
                av.w = f2bf(af32[3 * 4 + j] * wk);
                bv.x = f2bf(bf32[0 * 4 + j]);
                bv.y = f2bf(bf32[1 * 4 + j]);
                bv.z = f2bf(bf32[2 * 4 + j]);
                bv.w = f2bf(bf32[3 * 4 + j]);
                *(short4*)&AsB[1 - cur][(cq + j) * LDSS + kq] = av;
                *(short4*)&BsB[1 - cur][(cq + j) * LDSS + kq] = bv;
            }
            __syncthreads();
        }
    }

    // ---- epilogue: phased LDS dump + pair gather ----
    // C/D layout: within wave, local c0 = mi*16 + qd*4 + r, local c1 = ni*16 + ml
    const int myphase = wv >> 1, mybuf = wv & 1;
#pragma unroll 1
    for (int ph = 0; ph < 4; ++ph) {
        __syncthreads();          // prior reads of gat / staging LDS complete
        if (myphase == ph) {
            float* dst = gat + mybuf * 8256;   // 64 rows x 129 floats
#pragma unroll
            for (int mi = 0; mi < 4; ++mi)
#pragma unroll
                for (int ni = 0; ni < 8; ++ni)
#pragma unroll
                    for (int r = 0; r < 4; ++r)
                        dst[(mi * 16 + qd * 4 + r) * 129 + (ni * 16 + ml)] = acc[mi][ni][r];
        }
        __syncthreads();
#pragma unroll
        for (int i = t; i < 1024; i += 512) {
            const int pr = pairs[i];
            const int c0 = pr >> 8, c1 = pr & 255;
            const int own = (c0 >> 6) | ((c1 >> 7) << 2);
            if ((own >> 1) == ph) {
                const float v = gat[(own & 1) * 8256 + (c0 & 63) * 129 + (c1 & 127)];
#if defined(__gfx950__) || defined(__AMDGCN__)
                unsafeAtomicAdd(&S_b[i], v);
#else
                atomicAdd(&S_b[i], v);
#endif
            }
        }
    }

    // ---- last-block-done: compute logs in-kernel ----
    __threadfence();
    if (t == 0) lastFlag = (atomicAdd(counter, 1) == SPLITS - 1);
    __syncthreads();
    if (lastFlag) {
        __threadfence();   // acquire side
#pragma unroll
        for (int i = t; i < 1024; i += 512) {
            const float s = __hip_atomic_load(&S_b[i], __ATOMIC_RELAXED,
                                              __HIP_MEMORY_SCOPE_AGENT);
            out[i] = logf(s);
        }
    }
}

extern "C" void kernel_launch(void* const* d_in, const int* in_sizes, int n_in,
                              void* d_out, int out_size, void* d_ws, size_t ws_size,
                              hipStream_t stream)
{
    const int*   x    = (const int*)d_in[0];     // [1024,2] int32
    const float* W    = (const float*)d_in[1];   // [2,256,256,256] fp32
    const float* wsum = (const float*)d_in[2];   // [256] fp32
    float* out = (float*)d_out;                  // [1024] fp32

    float* S_b     = (float*)d_ws;               // 1024 floats
    int*   counter = (int*)d_ws + 1024;

    hipMemsetAsync(d_ws, 0, 1024 * sizeof(float) + sizeof(int), stream);
    hclt_fused_kernel<<<dim3(SPLITS), 512, 0, stream>>>(x, W, wsum, S_b, counter, out);
}

// Round 5
// 220.334 us; speedup vs baseline: 1.1229x; 1.1229x over previous
//
#include <hip/hip_runtime.h>
#include <math.h>

// out[b] = log( sum_kk (w[kk>>8]*W0[kk,x0[b]]) * W1[kk,x1[b]] ),  kk in [0,65536)
//
// gemm: 256 blocks (1/CU), 512 threads, split = 256 kk (one latent k -> w_sum
// block-uniform). BK=64 (LDS row = 128 B = full bank rotation) with XOR
// swizzle -> staging stores and fragment reads both conflict-free b128.
// Register-prefetch of iter+1. Epilogue: per-wave LDS dump (8 phases) +
// gather of the 1024 observed pairs -> plain coalesced store to P[split][1024]
// (NO atomics). finish: reduce 256 partials per output + log.

#define NBLK    256
#define KCHUNK  256
#define BK      64
#define NITER   (KCHUNK / BK)   // 4

typedef float  f32x4  __attribute__((ext_vector_type(4)));
typedef short  bf16x8 __attribute__((ext_vector_type(8)));

static __device__ __forceinline__ short f2bf(float f) {
    // RNE fp32 -> bf16 (positive probabilities; no NaN/Inf)
    unsigned u = __builtin_bit_cast(unsigned, f);
    u += 0x7fffu + ((u >> 16) & 1u);
    return (short)(u >> 16);
}

// LDS row = 64 bf16 = 32 dwords = 8 groups of 4 dwords. Swizzled group id:
// spreads staging stores (c>>2 = lane) and frag reads (c low bits = ml) over
// all 8 bank-groups -> uniform 8-deep = conflict-free for b128 ops.
static __device__ __forceinline__ int swz(int c) {
    return ((c >> 2) & 7) ^ ((c & 1) << 2);
}

__global__ __launch_bounds__(512, 2) void hclt_gemm(
    const int* __restrict__ x, const float* __restrict__ W,
    const float* __restrict__ wsum, float* __restrict__ P)
{
    __shared__ __align__(16) char smem[65536];   // As 32K | Bs 32K ; epilogue reuses as G[64][130]
    __shared__ int pairs[1024];

    char*  const AsB = smem;
    char*  const BsB = smem + 32768;
    float* const G   = (float*)smem;

    const int  blk   = blockIdx.x;             // 0..255
    const long kbase = (long)blk * KCHUNK;
    const float wk   = wsum[blk];              // block-uniform

    const float* __restrict__ Ag = W + kbase * 256;              // W0 rows
    const float* __restrict__ Bg = W + 16777216 + kbase * 256;   // W1 rows

    const int t    = threadIdx.x;
    const int lane = t & 63;
    const int wv   = t >> 6;                   // wave 0..7

    // observed pairs -> LDS (used only in the epilogue)
    {
        const int2 p0 = ((const int2*)x)[t];
        const int2 p1 = ((const int2*)x)[t + 512];
        pairs[t]       = (p0.x << 8) | p0.y;
        pairs[t + 512] = (p1.x << 8) | p1.y;
    }

    // staging geometry: thread owns c = cq..cq+3 at k-octet g0 (8 k's)
    const int cq = lane * 4;
    const int g0 = wv;                         // octet 0..7 within BK=64

    // compute geometry: wave tile 64(c0) x 128(c1)
    const int wc0 = (wv & 3) * 64;
    const int wc1 = (wv >> 2) * 128;
    const int ml  = lane & 15;
    const int qd  = lane >> 4;

    f32x4 acc[4][8];
#pragma unroll
    for (int i = 0; i < 4; ++i)
#pragma unroll
        for (int j = 0; j < 8; ++j) acc[i][j] = (f32x4){0.f, 0.f, 0.f, 0.f};

    float4 a4[8], b4[8];

    // ---- prologue: load + stage iter 0 ----
#pragma unroll
    for (int r = 0; r < 8; ++r) {
        a4[r] = *(const float4*)(Ag + (long)(g0 * 8 + r) * 256 + cq);
        b4[r] = *(const float4*)(Bg + (long)(g0 * 8 + r) * 256 + cq);
    }
#pragma unroll
    for (int j = 0; j < 4; ++j) {
        const int c = cq + j;
        bf16x8 av, bv;
#pragma unroll
        for (int r = 0; r < 8; ++r) {
            av[r] = f2bf(((const float*)&a4[r])[j] * wk);
            bv[r] = f2bf(((const float*)&b4[r])[j]);
        }
        const int off = c * 128 + (g0 ^ swz(c)) * 16;
        *(bf16x8*)(AsB + off) = av;
        *(bf16x8*)(BsB + off) = bv;
    }
    __syncthreads();

    // ---- main loop ----
#pragma unroll
    for (int it = 0; it < NITER; ++it) {
        if (it + 1 < NITER) {                  // prefetch next iter into regs
#pragma unroll
            for (int r = 0; r < 8; ++r) {
                a4[r] = *(const float4*)(Ag + (long)((it + 1) * BK + g0 * 8 + r) * 256 + cq);
                b4[r] = *(const float4*)(Bg + (long)((it + 1) * BK + g0 * 8 + r) * 256 + cq);
            }
        }
        // compute current iter from LDS: 2 k-steps of 32 each
#pragma unroll
        for (int s = 0; s < 2; ++s) {
            bf16x8 afr[4];
#pragma unroll
            for (int mi = 0; mi < 4; ++mi) {
                const int c = wc0 + mi * 16 + ml;
                afr[mi] = *(const bf16x8*)(AsB + c * 128 + (((s << 2) + qd) ^ swz(c)) * 16);
            }
#pragma unroll
            for (int ni = 0; ni < 8; ++ni) {
                const int c = wc1 + ni * 16 + ml;
                const bf16x8 bfr =
                    *(const bf16x8*)(BsB + c * 128 + (((s << 2) + qd) ^ swz(c)) * 16);
#pragma unroll
                for (int mi = 0; mi < 4; ++mi)
                    acc[mi][ni] = __builtin_amdgcn_mfma_f32_16x16x32_bf16(
                        afr[mi], bfr, acc[mi][ni], 0, 0, 0);
            }
        }
        if (it + 1 < NITER) {
            __syncthreads();                   // everyone done reading LDS
#pragma unroll
            for (int j = 0; j < 4; ++j) {
                const int c = cq + j;
                bf16x8 av, bv;
#pragma unroll
                for (int r = 0; r < 8; ++r) {
                    av[r] = f2bf(((const float*)&a4[r])[j] * wk);
                    bv[r] = f2bf(((const float*)&b4[r])[j]);
                }
                const int off = c * 128 + (g0 ^ swz(c)) * 16;
                *(bf16x8*)(AsB + off) = av;
                *(bf16x8*)(BsB + off) = bv;
            }
            __syncthreads();
        }
    }

    // ---- epilogue: 8 phases, one wave dumps its 64x128 tile, all gather ----
    // C/D layout: local c0 = mi*16 + qd*4 + r, local c1 = ni*16 + ml
    float v0 = 0.f, v1 = 0.f;
#pragma unroll 1
    for (int ph = 0; ph < 8; ++ph) {
        __syncthreads();
        if (wv == ph) {
#pragma unroll
            for (int mi = 0; mi < 4; ++mi)
#pragma unroll
                for (int ni = 0; ni < 8; ++ni)
#pragma unroll
                    for (int r = 0; r < 4; ++r)
                        G[(mi * 16 + qd * 4 + r) * 130 + (ni * 16 + ml)] = acc[mi][ni][r];
        }
        __syncthreads();
        {
            int pr = pairs[t];
            int c0 = pr >> 8, c1 = pr & 255;
            if ((((c0 >> 6) & 3) | ((c1 >> 7) << 2)) == ph)
                v0 = G[(c0 & 63) * 130 + (c1 & 127)];
            pr = pairs[t + 512];
            c0 = pr >> 8; c1 = pr & 255;
            if ((((c0 >> 6) & 3) | ((c1 >> 7) << 2)) == ph)
                v1 = G[(c0 & 63) * 130 + (c1 & 127)];
        }
    }
    P[(size_t)blk * 1024 + t]       = v0;      // coalesced, no atomics
    P[(size_t)blk * 1024 + 512 + t] = v1;
}

// Reduce the 256 per-split partials for each output, take log.
__global__ __launch_bounds__(256) void hclt_finish(
    const float* __restrict__ P, float* __restrict__ out)
{
    const int i = blockIdx.x * 256 + threadIdx.x;   // 4 x 256 = 1024
    float s0 = 0.f, s1 = 0.f, s2 = 0.f, s3 = 0.f;
#pragma unroll 8
    for (int s = 0; s < NBLK; s += 4) {             // lane-coalesced per s
        s0 += P[(size_t)(s + 0) * 1024 + i];
        s1 += P[(size_t)(s + 1) * 1024 + i];
        s2 += P[(size_t)(s + 2) * 1024 + i];
        s3 += P[(size_t)(s + 3) * 1024 + i];
    }
    out[i] = logf((s0 + s1) + (s2 + s3));
}

extern "C" void kernel_launch(void* const* d_in, const int* in_sizes, int n_in,
                              void* d_out, int out_size, void* d_ws, size_t ws_size,
                              hipStream_t stream)
{
    const int*   x    = (const int*)d_in[0];     // [1024,2] int32
    const float* W    = (const float*)d_in[1];   // [2,256,256,256] fp32
    const float* wsum = (const float*)d_in[2];   // [256] fp32
    float* out = (float*)d_out;                  // [1024] fp32

    float* P = (float*)d_ws;                     // 256 x 1024 floats = 1 MB

    hclt_gemm<<<dim3(NBLK), 512, 0, stream>>>(x, W, wsum, P);
    hclt_finish<<<dim3(4), 256, 0, stream>>>(P, out);
}